// Round 6
// baseline (284.109 us; speedup 1.0000x reference)
//
#include <hip/hip_runtime.h>

// QuantumRNNCell v8: fused, barrier-free, wave-owns-row streaming epilogue.
//
//   Ledger: v3/v4.1/v5/v6 all pin at ~2.45 TB/s; v7 (loads-before-stores but
//   16-MB-strided rows + 16 waves/CU) regressed to 1.75. This is the clean
//   test of counted-vmcnt + locality:
//     - 8192 blocks x 256 thr; wave (bid,wv) fully owns row bid*4+wv
//       (block = 16 KB contiguous; wave walks its 4-KB row in 4 chunks of
//       256 B stride = same DRAM page).
//     - NO LDS, NO barriers: q expvals live in lanes 0..5 of one VGPR,
//       broadcast via v_readlane at use.
//     - chunk loop fully unrolled; chunk c+1's weight/bias/hx loads are
//       issued BEFORE chunk c's store -> every wait-for-load has only
//       YOUNGER stores outstanding -> compiler emits counted vmcnt(N>0),
//       stores never drain the pipe.
//     - chunk-0 loads + x angle issued before the sim (~500 VALU instrs
//       hide the ramp).
//
// Fixed shape: B = 32768, H = 1024 (256 float4 per row).

#define NQ 6

typedef float floatx4 __attribute__((ext_vector_type(4)));

__device__ __forceinline__ float rl(float v, int lane) {
    return __int_as_float(__builtin_amdgcn_readlane(__float_as_int(v), lane));
}

__global__ __launch_bounds__(256, 4) void qrnn_fused_kernel(
    const float* __restrict__ x,     // (B, 6)
    const float* __restrict__ hx,    // (B, H)
    const float* __restrict__ qw,    // (3, 6)
    const float* __restrict__ fc_w,  // (H, 6)
    const float* __restrict__ fc_b,  // (H,)
    float* __restrict__ out)         // (B, H)
{
    const int tid = threadIdx.x;
    const int l   = tid & 63;                  // lane = basis state
    const int wv  = tid >> 6;                  // wave 0..3
    const int r   = blockIdx.x * 4 + wv;       // this wave's OWN row

    const float4* hx4 = (const float4*)hx;
    const float4* w4  = (const float4*)fc_w;
    const float4* b4  = (const float4*)fc_b;
    floatx4* out4 = (floatx4*)out;

    // ---- phase 0: x angle + chunk-0 epilogue loads, all issued up front ----
    const float angx = (l < 6) ? x[(size_t)r * NQ + l] : 0.f;
    int cb = l;                                // chunk-0 column for this lane
    float4 a0 = w4[cb * 6 + 0], a1 = w4[cb * 6 + 1], a2 = w4[cb * 6 + 2];
    float4 a3 = w4[cb * 6 + 3], a4 = w4[cb * 6 + 4], a5 = w4[cb * 6 + 5];
    float4 bv = b4[cb];
    float4 h  = hx4[(size_t)r * 256 + cb];

    // ---- phase 1: wave-parallel sim (verbatim v6 math) ----
    const float angq = (l >= 6 && l < 24) ? qw[l - 6] : 0.f;
    float saq, caq;
    __sincosf(angq * 0.5f, &saq, &caq);

    float sax, cax;
    __sincosf(angx * 0.5f, &sax, &cax);
    float cx[6], sx[6];
    #pragma unroll
    for (int i = 0; i < 6; ++i) { cx[i] = rl(cax, i); sx[i] = rl(sax, i); }

    float re = (l == 0) ? 1.f : 0.f;
    float im = 0.f;

    // encoding: RX(x[i]), RY(x[i+1]), RZ(x[i+2]) on wire i (bit 5-i)
    #pragma unroll
    for (int w = 0; w < 6; ++w) {
        const int m = 1 << (5 - w);
        const float sgn = (l & m) ? 1.f : -1.f;
        float pr = __shfl_xor(re, m), pi = __shfl_xor(im, m);
        float c = cx[w], s = sx[w];
        float nr = c * re + s * pi;
        float ni = c * im - s * pr;
        re = nr; im = ni;
        pr = __shfl_xor(re, m); pi = __shfl_xor(im, m);
        c = cx[(w + 1) % 6]; s = sx[(w + 1) % 6] * sgn;
        nr = c * re + s * pr;
        ni = c * im + s * pi;
        re = nr; im = ni;
        c = cx[(w + 2) % 6];
        const float sg = (l & m) ? -sx[(w + 2) % 6] : sx[(w + 2) % 6];
        nr = c * re + sg * im;
        ni = c * im - sg * re;
        re = nr; im = ni;
    }

    // CNOT-ring composed permutation: new[l] = old[src]
    int src = l;
    #pragma unroll
    for (int q = 5; q >= 0; --q) {
        const int cbit = 5 - q, tbit = 5 - ((q + 1) % 6);
        src ^= ((src >> cbit) & 1) << tbit;
    }

    // variational layers: 6x RY(qw[lay][q]) then CNOT ring
    #pragma unroll
    for (int lay = 0; lay < 3; ++lay) {
        #pragma unroll
        for (int q = 0; q < 6; ++q) {
            const int m = 1 << (5 - q);
            const float c = rl(caq, 6 + lay * 6 + q);
            const float s = rl(saq, 6 + lay * 6 + q);
            const float sg = (l & m) ? s : -s;
            const float pr = __shfl_xor(re, m), pi = __shfl_xor(im, m);
            const float nr = c * re + sg * pr;
            const float ni = c * im + sg * pi;
            re = nr; im = ni;
        }
        re = __shfl(re, src);
        im = __shfl(im, src);
    }

    // probabilities -> 6-stage Walsh-Hadamard; q[j] lands at lane 32>>j
    float p = re * re + im * im;
    #pragma unroll
    for (int k = 0; k < 6; ++k) {
        const int m = 1 << k;
        const float t = __shfl_xor(p, m);
        p = (l & m) ? (t - p) : (t + p);
    }
    const int srcl = (l < 6) ? (32 >> l) : 0;
    const float qv = __shfl(p, srcl);          // lanes 0..5 hold q0..q5
    const float q0 = rl(qv, 0), q1 = rl(qv, 1), q2 = rl(qv, 2);
    const float q3 = rl(qv, 3), q4 = rl(qv, 4), q5 = rl(qv, 5);

    // ---- phase 2: stream own row, loads of chunk c+1 before store of c ----
    #pragma unroll
    for (int c = 0; c < 4; ++c) {
        float4 na0, na1, na2, na3, na4, na5, nbv, nh;
        if (c < 3) {                           // issue next chunk's loads NOW
            const int nc = (c + 1) * 64 + l;
            na0 = w4[nc * 6 + 0]; na1 = w4[nc * 6 + 1]; na2 = w4[nc * 6 + 2];
            na3 = w4[nc * 6 + 3]; na4 = w4[nc * 6 + 4]; na5 = w4[nc * 6 + 5];
            nbv = b4[nc];
            nh  = hx4[(size_t)r * 256 + nc];
        }
        floatx4 res;
        res.x = h.x + bv.x + q0*a0.x + q1*a0.y + q2*a0.z + q3*a0.w + q4*a1.x + q5*a1.y;
        res.y = h.y + bv.y + q0*a1.z + q1*a1.w + q2*a2.x + q3*a2.y + q4*a2.z + q5*a2.w;
        res.z = h.z + bv.z + q0*a3.x + q1*a3.y + q2*a3.z + q3*a3.w + q4*a4.x + q5*a4.y;
        res.w = h.w + bv.w + q0*a4.z + q1*a4.w + q2*a5.x + q3*a5.y + q4*a5.z + q5*a5.w;
        __builtin_nontemporal_store(res, &out4[(size_t)r * 256 + c * 64 + l]);
        if (c < 3) {
            a0 = na0; a1 = na1; a2 = na2; a3 = na3; a4 = na4; a5 = na5;
            bv = nbv; h = nh;
        }
    }
}

extern "C" void kernel_launch(void* const* d_in, const int* in_sizes, int n_in,
                              void* d_out, int out_size, void* d_ws, size_t ws_size,
                              hipStream_t stream) {
    const float* x    = (const float*)d_in[0];   // (B, 6)
    const float* hx   = (const float*)d_in[1];   // (B, H)
    const float* qw   = (const float*)d_in[2];   // (3, 6)
    const float* fc_w = (const float*)d_in[3];   // (H, 6)
    const float* fc_b = (const float*)d_in[4];   // (H,)
    float* out = (float*)d_out;

    const int B = in_sizes[0] / NQ;              // 32768
    // H fixed at 1024 (kernel hardcodes 256 float4 per row)
    (void)d_ws; (void)ws_size;

    // one wave per row, 4 rows per block -> 8192 blocks, 32 waves/CU offered
    qrnn_fused_kernel<<<B / 4, 256, 0, stream>>>(x, hx, qw, fc_w, fc_b, out);
}